// Round 9
// baseline (144.616 us; speedup 1.0000x reference)
//
#include <hip/hip_runtime.h>

#define NB    8
#define NH    16384
#define NL    2048
#define F_HR  64
#define F_LR  128
#define OUT_COLS 198   // 64 + 3 + 128 + 3

// ---------------------------------------------------------------------------
// Prep kernel: candidate table (x, y, z, 0.5*|p|^2) into global scratch.
// Expression text identical to the proven R3 staging (same contraction).
// ---------------------------------------------------------------------------
__global__ __launch_bounds__(256) void prep_kernel(
    const float* __restrict__ pos_lr,   // [NB*NL, 3]
    float4* __restrict__ cand)          // [NB*NL]
{
    const int t = blockIdx.x * 256 + threadIdx.x;   // 16384 threads total
    const float x = pos_lr[t * 3 + 0];
    const float y = pos_lr[t * 3 + 1];
    const float z = pos_lr[t * 3 + 2];
    cand[t] = make_float4(x, y, z, 0.5f * ((x * x + y * y) + z * z));
}

// ---------------------------------------------------------------------------
// Kernel A: argmin over batch's 2048 candidates.
// R8 diagnosis: LDS-broadcast reads bound the kernel (2048 ds_read_b128/wave
// x 8 waves/CU x ~9.5cyc = 62.5 us). Candidate address is WAVE-UNIFORM ->
// read from global via s_load_dwordx4 (scalar pipe, K$-resident 32KB batch),
// freeing the LDS pipe entirely. Explicit next-8 prefetch (SGPR double
// buffer) hides SMEM latency. Key formula textually identical to R3 (proven:
// all 131072 argmins match numpy, absmax 0 across 5 rounds).
// ---------------------------------------------------------------------------
__global__ __launch_bounds__(256) void knn_kernel(
    const float* __restrict__ pos_hr,   // [NB*NH, 3]
    const float4* __restrict__ cand,    // [NB*NL] (x,y,z,halfsq)
    int* __restrict__ out_idx)          // [NB*NH]
{
    const int blocksPerBatch = NH / 256;              // 64
    const int b = blockIdx.x / blocksPerBatch;
    const int rowInBatch = (blockIdx.x % blocksPerBatch) * 256 + threadIdx.x;

    const float4* __restrict__ cb = cand + b * NL;    // uniform base

    const int hr = b * NH + rowInBatch;
    const float phx = pos_hr[hr * 3 + 0];
    const float phy = pos_hr[hr * 3 + 1];
    const float phz = pos_hr[hr * 3 + 2];

    float best[8];
    int   bi[8];
#pragma unroll
    for (int k = 0; k < 8; ++k) { best[k] = 3.4e38f; bi[k] = k; }

    // SGPR double buffer: prefetch next 8 candidates during compute
    float4 cn[8];
#pragma unroll
    for (int k = 0; k < 8; ++k) cn[k] = cb[k];

    for (int j = 0; j < NL; j += 8) {
        float4 c[8];
#pragma unroll
        for (int k = 0; k < 8; ++k) c[k] = cn[k];

        const int jn = (j + 8 < NL) ? j + 8 : 0;      // wrap: last prefetch unused
#pragma unroll
        for (int k = 0; k < 8; ++k) cn[k] = cb[jn + k];

#pragma unroll
        for (int k = 0; k < 8; ++k) {
            float d = fmaf(-phz, c[k].z, fmaf(-phy, c[k].y, fmaf(-phx, c[k].x, c[k].w)));
            if (d < best[k]) { best[k] = d; bi[k] = j + k; }   // strict <: first wins
        }
    }

    float bestv = best[0]; int bestidx = bi[0];
#pragma unroll
    for (int k = 1; k < 8; ++k) {
        if (best[k] < bestv || (best[k] == bestv && bi[k] < bestidx)) {
            bestv = best[k]; bestidx = bi[k];
        }
    }

    out_idx[hr] = b * NL + bestidx;
}

// ---------------------------------------------------------------------------
// Kernel B: PHASE-SPLIT assemble (R8, proven 32.4 us timed). DO NOT TOUCH.
// P1: 11 independent idx loads; P2: 11 gathers (counted vmcnt waits, loads
// stay pipelined); P3: 11 coalesced stores. Incremental row/col decode.
// ---------------------------------------------------------------------------
#define GRID_B   3072
#define NTHREADS (GRID_B * 256)                 // 786,432
// R0 = 8*16384*198 = 25,952,256 = 33 * NTHREADS exactly -> no bounds checks
#define ROW_STEP 3971                           // 786432 / 198
#define COL_STEP 174                            // 786432 % 198
#define BATCH    11                             // 33 = 3 * 11

__global__ __launch_bounds__(256) void assemble_kernel(
    const float* __restrict__ x_hr,     // [NB*NH, 64]
    const float* __restrict__ pos_hr,   // [NB*NH, 3]
    const float* __restrict__ x_lr,     // [NB*NL, 128]
    const float* __restrict__ pos_lr,   // [NB*NL, 3]
    const int* __restrict__ idx,        // [NB*NH]
    float* __restrict__ out)
{
    const int R0 = NB * NH * OUT_COLS;        // 25,952,256
    const int Z  = NB * NH * 3;               // 393,216 zeros after R0
    const int TAIL = Z + NB * NH;             // 524,288 total tail elems

    const int tid = blockIdx.x * blockDim.x + threadIdx.x;

    int row = tid / OUT_COLS;                 // one division per thread
    int col = tid - row * OUT_COLS;

    for (int b = 0; b < 3; ++b) {
        int   rs[BATCH], cs[BATCH], ls[BATCH];
        float vs[BATCH];

#pragma unroll
        for (int k = 0; k < BATCH; ++k) {
            rs[k] = row;
            cs[k] = col;
            ls[k] = idx[row];
            col += COL_STEP;
            const int carry = (col >= OUT_COLS) ? 1 : 0;
            col -= carry ? OUT_COLS : 0;
            row += ROW_STEP + carry;
        }

#pragma unroll
        for (int k = 0; k < BATCH; ++k) {
            const int c = cs[k];
            const float* a =
                  c < F_HR            ? x_hr   + rs[k] * F_HR + c
                : c < F_HR + 3        ? pos_hr + rs[k] * 3    + (c - F_HR)
                : c < F_HR + 3 + F_LR ? x_lr   + ls[k] * F_LR + (c - (F_HR + 3))
                :                       pos_lr + ls[k] * 3    + (c - (F_HR + 3 + F_LR));
            vs[k] = *a;
        }

#pragma unroll
        for (int k = 0; k < BATCH; ++k) {
            out[tid + (b * BATCH + k) * NTHREADS] = vs[k];
        }
    }

    if (tid < TAIL) {
        const float v = tid < Z ? 0.0f : (float)((tid - Z) >> 14);  // NH = 2^14
        out[R0 + tid] = v;
    }
}

extern "C" void kernel_launch(void* const* d_in, const int* in_sizes, int n_in,
                              void* d_out, int out_size, void* d_ws, size_t ws_size,
                              hipStream_t stream) {
    const float* x_hr   = (const float*)d_in[0];
    const float* pos_hr = (const float*)d_in[1];
    // d_in[2] = batch_hr (int32) — unused, batch is contiguous repeats
    const float* x_lr   = (const float*)d_in[3];
    const float* pos_lr = (const float*)d_in[4];
    // d_in[5] = batch_lr (int32) — unused

    int*    idx  = (int*)d_ws;                              // 512 KiB
    float4* cand = (float4*)((char*)d_ws + NB * NH * 4);    // +256 KiB, 16B-aligned

    prep_kernel<<<dim3(NB * NL / 256), dim3(256), 0, stream>>>(pos_lr, cand);
    knn_kernel<<<dim3(NB * NH / 256), dim3(256), 0, stream>>>(pos_hr, cand, idx);
    assemble_kernel<<<dim3(GRID_B), dim3(256), 0, stream>>>(
        x_hr, pos_hr, x_lr, pos_lr, idx, (float*)d_out);
}

// Round 10
// 106.211 us; speedup vs baseline: 1.3616x; 1.3616x over previous
//
#include <hip/hip_runtime.h>

#define NB    8
#define NH    16384
#define NL    2048
#define F_HR  64
#define F_LR  128
#define OUT_COLS 198   // 64 + 3 + 128 + 3

// ---------------------------------------------------------------------------
// Kernel A: split-K coarsened argmin.
// R8 model (verified): LDS-broadcast ds_read_b128 costs ~9.2 cyc regardless
// of broadcast -> 8 waves/CU x 2048 reads = 62.5 us LDS-bound. R9: SMEM path
// refuted (compiler won't scalarize global loads). Fix: amortize each LDS
// read over M=4 points (4x fewer waves); keep 256 blocks (1/CU) by splitting
// candidates into halves. Per block: 1024 points x 1024 candidates, 4 waves.
// LDS/CU ~15.7us, VALU ~20.5us -> VALU-bound ~24us.
// Key formula textually identical to R3-R8 (proven: argmins match numpy).
// Partial (val,idx) per (point,half) -> d_out tail scratch (exactly the
// 524288-float tail region, later overwritten by assemble).
// ---------------------------------------------------------------------------
__global__ __launch_bounds__(256) void knn_split_kernel(
    const float* __restrict__ pos_hr,   // [NB*NH, 3]
    const float* __restrict__ pos_lr,   // [NB*NL, 3]
    float* __restrict__ pscr)           // [131072*4] (v0,i0,v1,i1) per point
{
    __shared__ float4 lds[1024];        // 16 KiB: (x, y, z, 0.5*|p|^2)

    const int h = blockIdx.x & 1;       // candidate half
    const int g = blockIdx.x >> 1;      // point group (1024 points), [0,128)
    const int b = g >> 4;               // batch (16 groups per batch)

    const float* pl = pos_lr + ((size_t)b * NL + (h << 10)) * 3;
    for (int j = threadIdx.x; j < 1024; j += 256) {
        float x = pl[j * 3 + 0];
        float y = pl[j * 3 + 1];
        float z = pl[j * 3 + 2];
        lds[j] = make_float4(x, y, z, 0.5f * ((x * x + y * y) + z * z));
    }
    __syncthreads();

    // M=4 points per thread (stride 256 within the group)
    float phx[4], phy[4], phz[4];
    float best[4][4];
    int   bi[4][4];
#pragma unroll
    for (int m = 0; m < 4; ++m) {
        const int pt = (g << 10) + threadIdx.x + (m << 8);
        phx[m] = pos_hr[pt * 3 + 0];
        phy[m] = pos_hr[pt * 3 + 1];
        phz[m] = pos_hr[pt * 3 + 2];
#pragma unroll
        for (int k = 0; k < 4; ++k) { best[m][k] = 3.4e38f; bi[m][k] = k; }
    }

    for (int j = 0; j < 1024; j += 4) {
        float4 c[4];
#pragma unroll
        for (int k = 0; k < 4; ++k) c[k] = lds[j + k];
#pragma unroll
        for (int m = 0; m < 4; ++m) {
#pragma unroll
            for (int k = 0; k < 4; ++k) {
                float d = fmaf(-phz[m], c[k].z,
                         fmaf(-phy[m], c[k].y,
                         fmaf(-phx[m], c[k].x, c[k].w)));
                if (d < best[m][k]) { best[m][k] = d; bi[m][k] = j + k; }  // strict <
            }
        }
    }

#pragma unroll
    for (int m = 0; m < 4; ++m) {
        float bv = best[m][0]; int bidx = bi[m][0];
#pragma unroll
        for (int k = 1; k < 4; ++k) {
            if (best[m][k] < bv || (best[m][k] == bv && bi[m][k] < bidx)) {
                bv = best[m][k]; bidx = bi[m][k];
            }
        }
        const int pt = (g << 10) + threadIdx.x + (m << 8);
        pscr[pt * 4 + h * 2 + 0] = bv;
        pscr[pt * 4 + h * 2 + 1] = __int_as_float(b * NL + (h << 10) + bidx);
    }
}

// ---------------------------------------------------------------------------
// Merge halves: half0 wins ties (lower global index = first occurrence).
// ---------------------------------------------------------------------------
__global__ __launch_bounds__(256) void merge_kernel(
    const float* __restrict__ pscr,     // [131072*4]
    int* __restrict__ idx)              // [NB*NH]
{
    const int t = blockIdx.x * 256 + threadIdx.x;   // 131072 threads
    const float4 p = *(const float4*)&pscr[t * 4];
    const float v0 = p.x; const int i0 = __float_as_int(p.y);
    const float v1 = p.z; const int i1 = __float_as_int(p.w);
    idx[t] = (v1 < v0) ? i1 : i0;
}

// ---------------------------------------------------------------------------
// Kernel B: PHASE-SPLIT assemble (R8, proven 32.4 us timed). DO NOT TOUCH.
// ---------------------------------------------------------------------------
#define GRID_B   3072
#define NTHREADS (GRID_B * 256)                 // 786,432
// R0 = 8*16384*198 = 25,952,256 = 33 * NTHREADS exactly -> no bounds checks
#define ROW_STEP 3971                           // 786432 / 198
#define COL_STEP 174                            // 786432 % 198
#define BATCH    11                             // 33 = 3 * 11

__global__ __launch_bounds__(256) void assemble_kernel(
    const float* __restrict__ x_hr,     // [NB*NH, 64]
    const float* __restrict__ pos_hr,   // [NB*NH, 3]
    const float* __restrict__ x_lr,     // [NB*NL, 128]
    const float* __restrict__ pos_lr,   // [NB*NL, 3]
    const int* __restrict__ idx,        // [NB*NH]
    float* __restrict__ out)
{
    const int R0 = NB * NH * OUT_COLS;        // 25,952,256
    const int Z  = NB * NH * 3;               // 393,216 zeros after R0
    const int TAIL = Z + NB * NH;             // 524,288 total tail elems

    const int tid = blockIdx.x * blockDim.x + threadIdx.x;

    int row = tid / OUT_COLS;                 // one division per thread
    int col = tid - row * OUT_COLS;

    for (int b = 0; b < 3; ++b) {
        int   rs[BATCH], cs[BATCH], ls[BATCH];
        float vs[BATCH];

#pragma unroll
        for (int k = 0; k < BATCH; ++k) {
            rs[k] = row;
            cs[k] = col;
            ls[k] = idx[row];
            col += COL_STEP;
            const int carry = (col >= OUT_COLS) ? 1 : 0;
            col -= carry ? OUT_COLS : 0;
            row += ROW_STEP + carry;
        }

#pragma unroll
        for (int k = 0; k < BATCH; ++k) {
            const int c = cs[k];
            const float* a =
                  c < F_HR            ? x_hr   + rs[k] * F_HR + c
                : c < F_HR + 3        ? pos_hr + rs[k] * 3    + (c - F_HR)
                : c < F_HR + 3 + F_LR ? x_lr   + ls[k] * F_LR + (c - (F_HR + 3))
                :                       pos_lr + ls[k] * 3    + (c - (F_HR + 3 + F_LR));
            vs[k] = *a;
        }

#pragma unroll
        for (int k = 0; k < BATCH; ++k) {
            out[tid + (b * BATCH + k) * NTHREADS] = vs[k];
        }
    }

    if (tid < TAIL) {
        const float v = tid < Z ? 0.0f : (float)((tid - Z) >> 14);  // NH = 2^14
        out[R0 + tid] = v;
    }
}

extern "C" void kernel_launch(void* const* d_in, const int* in_sizes, int n_in,
                              void* d_out, int out_size, void* d_ws, size_t ws_size,
                              hipStream_t stream) {
    const float* x_hr   = (const float*)d_in[0];
    const float* pos_hr = (const float*)d_in[1];
    // d_in[2] = batch_hr (int32) — unused, batch is contiguous repeats
    const float* x_lr   = (const float*)d_in[3];
    const float* pos_lr = (const float*)d_in[4];
    // d_in[5] = batch_lr (int32) — unused

    int*   idx  = (int*)d_ws;                            // 512 KiB scratch
    float* pscr = (float*)d_out + NB * NH * OUT_COLS;    // tail 524288 floats,
                                                         // overwritten by assemble

    knn_split_kernel<<<dim3(256), dim3(256), 0, stream>>>(pos_hr, pos_lr, pscr);
    merge_kernel<<<dim3(512), dim3(256), 0, stream>>>(pscr, idx);
    assemble_kernel<<<dim3(GRID_B), dim3(256), 0, stream>>>(
        x_hr, pos_hr, x_lr, pos_lr, idx, (float*)d_out);
}

// Round 11
// 77.532 us; speedup vs baseline: 1.8652x; 1.3699x over previous
//
#include <hip/hip_runtime.h>

#define NB    8
#define NH    16384
#define NL    2048
#define F_HR  64
#define F_LR  128
#define OUT_COLS 198   // 64 + 3 + 128 + 3

// ---------------------------------------------------------------------------
// Kernel A: coarsened argmin with in-block candidate split.
// Ladder so far: R8 62.5us = LDS-bound (1 ds_read_b128 per candidate per
// wave, 8 waves/CU); R9 SMEM refuted (no scalarization of uniform loads);
// R10 split-K 70.9us refuted 1-wave/SIMD (VALUBusy 52%, waits exposed).
// This design: block=512thr (8 waves), 256 points/block (M=4/lane), the 8
// waves each scan a DISJOINT 256-candidate slice -> 512 blocks = 2/CU =
// 16 waves/CU (4/SIMD, latency hidden). LDS reads/CU: 4096*9.2cyc=15.7us
// < VALU floor 20.5us (2.68e8 pairs x 6 ops) -> VALU-bound ~26us.
// Per-wave partials merged IN-BLOCK via LDS (ascending slice order + strict
// '<' == first-occurrence argmin). Key formula text identical to R3 (proven
// bit-exact vs numpy across 6 passing rounds).
// ---------------------------------------------------------------------------
__global__ __launch_bounds__(512, 4) void knn_kernel(
    const float* __restrict__ pos_hr,   // [NB*NH, 3]
    const float* __restrict__ pos_lr,   // [NB*NL, 3]
    int* __restrict__ out_idx)          // [NB*NH]
{
    __shared__ float4 cand[NL];         // 32 KiB (x, y, z, 0.5*|p|^2)
    __shared__ float  pval[8][256];     //  8 KiB per-wave best value
    __shared__ int    pidx[8][256];     //  8 KiB per-wave best index (batch-local)

    const int b  = blockIdx.x >> 6;     // 64 blocks per batch
    const int p0 = blockIdx.x << 8;     // first global point of this block
    const int w  = threadIdx.x >> 6;    // wave id = candidate slice
    const int l  = threadIdx.x & 63;

    // stage this batch's candidates (same formula text as proven R3 kernel)
    const float* pl = pos_lr + (size_t)b * NL * 3;
    for (int j = threadIdx.x; j < NL; j += 512) {
        float x = pl[j * 3 + 0];
        float y = pl[j * 3 + 1];
        float z = pl[j * 3 + 2];
        cand[j] = make_float4(x, y, z, 0.5f * ((x * x + y * y) + z * z));
    }
    __syncthreads();

    // M=4 points per lane (lane-stride 64 within the block's 256 points)
    float phx[4], phy[4], phz[4];
#pragma unroll
    for (int m = 0; m < 4; ++m) {
        const int pt = p0 + (m << 6) + l;
        phx[m] = pos_hr[pt * 3 + 0];
        phy[m] = pos_hr[pt * 3 + 1];
        phz[m] = pos_hr[pt * 3 + 2];
    }

    float best[4][2];
    int   bi[4][2];
#pragma unroll
    for (int m = 0; m < 4; ++m) {
        best[m][0] = 3.4e38f; best[m][1] = 3.4e38f;
        bi[m][0] = 0;         bi[m][1] = 1;
    }

    const int base = w << 8;            // this wave's slice start (batch-local)
    for (int j = 0; j < 256; j += 2) {
        const float4 c0 = cand[base + j];
        const float4 c1 = cand[base + j + 1];
#pragma unroll
        for (int m = 0; m < 4; ++m) {
            float d0 = fmaf(-phz[m], c0.z, fmaf(-phy[m], c0.y, fmaf(-phx[m], c0.x, c0.w)));
            float d1 = fmaf(-phz[m], c1.z, fmaf(-phy[m], c1.y, fmaf(-phx[m], c1.x, c1.w)));
            if (d0 < best[m][0]) { best[m][0] = d0; bi[m][0] = j; }     // strict <
            if (d1 < best[m][1]) { best[m][1] = d1; bi[m][1] = j + 1; }
        }
    }

    // k-merge (lower index wins ties), write per-wave partial to LDS
#pragma unroll
    for (int m = 0; m < 4; ++m) {
        float v = best[m][0]; int i = bi[m][0];
        if (best[m][1] < v || (best[m][1] == v && bi[m][1] < i)) {
            v = best[m][1]; i = bi[m][1];
        }
        const int ptl = (m << 6) + l;   // block-local point
        pval[w][ptl] = v;
        pidx[w][ptl] = base + i;        // batch-local candidate index
    }
    __syncthreads();

    // cross-wave merge: slices in ascending index order, strict < keeps first
    const int t = threadIdx.x;
    if (t < 256) {
        float v = pval[0][t]; int i = pidx[0][t];
#pragma unroll
        for (int q = 1; q < 8; ++q) {
            const float qv = pval[q][t];
            if (qv < v) { v = qv; i = pidx[q][t]; }
        }
        out_idx[p0 + t] = b * NL + i;
    }
}

// ---------------------------------------------------------------------------
// Kernel B: PHASE-SPLIT assemble (R8, proven 32.4 us timed). DO NOT TOUCH.
// P1: 11 independent idx loads; P2: 11 gathers (counted vmcnt waits keep
// loads pipelined); P3: 11 coalesced stores. Incremental row/col decode.
// ---------------------------------------------------------------------------
#define GRID_B   3072
#define NTHREADS (GRID_B * 256)                 // 786,432
// R0 = 8*16384*198 = 25,952,256 = 33 * NTHREADS exactly -> no bounds checks
#define ROW_STEP 3971                           // 786432 / 198
#define COL_STEP 174                            // 786432 % 198
#define BATCH    11                             // 33 = 3 * 11

__global__ __launch_bounds__(256) void assemble_kernel(
    const float* __restrict__ x_hr,     // [NB*NH, 64]
    const float* __restrict__ pos_hr,   // [NB*NH, 3]
    const float* __restrict__ x_lr,     // [NB*NL, 128]
    const float* __restrict__ pos_lr,   // [NB*NL, 3]
    const int* __restrict__ idx,        // [NB*NH]
    float* __restrict__ out)
{
    const int R0 = NB * NH * OUT_COLS;        // 25,952,256
    const int Z  = NB * NH * 3;               // 393,216 zeros after R0
    const int TAIL = Z + NB * NH;             // 524,288 total tail elems

    const int tid = blockIdx.x * blockDim.x + threadIdx.x;

    int row = tid / OUT_COLS;                 // one division per thread
    int col = tid - row * OUT_COLS;

    for (int b = 0; b < 3; ++b) {
        int   rs[BATCH], cs[BATCH], ls[BATCH];
        float vs[BATCH];

#pragma unroll
        for (int k = 0; k < BATCH; ++k) {
            rs[k] = row;
            cs[k] = col;
            ls[k] = idx[row];
            col += COL_STEP;
            const int carry = (col >= OUT_COLS) ? 1 : 0;
            col -= carry ? OUT_COLS : 0;
            row += ROW_STEP + carry;
        }

#pragma unroll
        for (int k = 0; k < BATCH; ++k) {
            const int c = cs[k];
            const float* a =
                  c < F_HR            ? x_hr   + rs[k] * F_HR + c
                : c < F_HR + 3        ? pos_hr + rs[k] * 3    + (c - F_HR)
                : c < F_HR + 3 + F_LR ? x_lr   + ls[k] * F_LR + (c - (F_HR + 3))
                :                       pos_lr + ls[k] * 3    + (c - (F_HR + 3 + F_LR));
            vs[k] = *a;
        }

#pragma unroll
        for (int k = 0; k < BATCH; ++k) {
            out[tid + (b * BATCH + k) * NTHREADS] = vs[k];
        }
    }

    if (tid < TAIL) {
        const float v = tid < Z ? 0.0f : (float)((tid - Z) >> 14);  // NH = 2^14
        out[R0 + tid] = v;
    }
}

extern "C" void kernel_launch(void* const* d_in, const int* in_sizes, int n_in,
                              void* d_out, int out_size, void* d_ws, size_t ws_size,
                              hipStream_t stream) {
    const float* x_hr   = (const float*)d_in[0];
    const float* pos_hr = (const float*)d_in[1];
    // d_in[2] = batch_hr (int32) — unused, batch is contiguous repeats
    const float* x_lr   = (const float*)d_in[3];
    const float* pos_lr = (const float*)d_in[4];
    // d_in[5] = batch_lr (int32) — unused

    int* idx = (int*)d_ws;                    // NB*NH ints = 512 KiB scratch

    knn_kernel<<<dim3(NB * NH / 256), dim3(512), 0, stream>>>(pos_hr, pos_lr, idx);
    assemble_kernel<<<dim3(GRID_B), dim3(256), 0, stream>>>(
        x_hr, pos_hr, x_lr, pos_lr, idx, (float*)d_out);
}